// Round 5
// baseline (332.551 us; speedup 1.0000x reference)
//
#include <hip/hip_runtime.h>

constexpr int B  = 2;
constexpr int NH = 8;
constexpr int L  = 512;
constexpr int D  = 64;
constexpr float INV_TEMP = 0.125f;   // 1/sqrt(D) = 1/8

// ---------------------------------------------------------------------------
// K1: S1[b,h,i,j] = (q[b,h,i,:]/8) . k[b,h,j,:]  -> d_ws   (unchanged)
// ---------------------------------------------------------------------------
__global__ __launch_bounds__(256) void k1_qk(const float* __restrict__ q,
                                             const float* __restrict__ k,
                                             float* __restrict__ s1) {
  const int bh = blockIdx.x, it = blockIdx.y, jt = blockIdx.z;
  __shared__ float Qs[64][68];    // stride 68: b128-aligned, 2-way banks (free)
  __shared__ float Ks[64][68];
  const int t = threadIdx.x;
  const float* qb = q + ((size_t)bh * L + it * 64) * D;
  const float* kb = k + ((size_t)bh * L + jt * 64) * D;
#pragma unroll
  for (int n0 = 0; n0 < 4; ++n0) {            // 64x64 = 1024 float4 each
    int n = t + (n0 << 8);
    int r = n >> 4, c = (n & 15) << 2;
    float4 a = *(const float4*)(qb + (size_t)r * D + c);
    a.x *= INV_TEMP; a.y *= INV_TEMP; a.z *= INV_TEMP; a.w *= INV_TEMP;
    *(float4*)&Qs[r][c] = a;
    *(float4*)&Ks[r][c] = *(const float4*)(kb + (size_t)r * D + c);
  }
  __syncthreads();
  const int i0 = t >> 4, j0 = t & 15;         // i = i0+16m, j = j0+16n
  float acc[4][4] = {};
#pragma unroll 1
  for (int kc = 0; kc < 64; kc += 4) {
    float4 a[4], b[4];
#pragma unroll
    for (int m = 0; m < 4; ++m) a[m] = *(const float4*)&Qs[i0 + 16 * m][kc];
#pragma unroll
    for (int n = 0; n < 4; ++n) b[n] = *(const float4*)&Ks[j0 + 16 * n][kc];
#pragma unroll
    for (int m = 0; m < 4; ++m)
#pragma unroll
      for (int n = 0; n < 4; ++n)
        acc[m][n] = fmaf(a[m].x, b[n].x,
                    fmaf(a[m].y, b[n].y,
                    fmaf(a[m].z, b[n].z,
                    fmaf(a[m].w, b[n].w, acc[m][n]))));
  }
  float* sb = s1 + ((size_t)bh * L + it * 64) * L + jt * 64;
#pragma unroll
  for (int m = 0; m < 4; ++m) {
    float* srow = sb + (size_t)(i0 + 16 * m) * L;
#pragma unroll
    for (int n = 0; n < 4; ++n) srow[j0 + 16 * n] = acc[m][n];
  }
}

// ---------------------------------------------------------------------------
// K2 v6: one block per (b,i), 512 threads, launch_bounds(512,4).
// Round-4 post-mortem: VGPR=44 -> ~2 loads in flight/wave -> 1.7 TB/s MLP
// cap. v6 manufactures MLP explicitly:
//  A: 2-deep chunk prefetch (named bufA/bufB, 2 chunks per unrolled iter;
//     each chunk's loads get >1000cy of cover before their vmcnt wait).
//     s1+mask for all 8 chunks hoisted into one up-front load burst.
//  B: softmax, head w per wave (unchanged, passed).
//  C: 16-deep register load batch of the wave's whole adj_v slice (64 VGPR,
//     static indices, sched_barrier-pinned burst) -> 256B/lane in flight,
//     then the FMA pass. Cross-wave combine via LDS (unchanged, passed).
// ---------------------------------------------------------------------------
#define K2_CHUNK(CC, BUF0, BUF1)                                              \
  {                                                                           \
    *(float4*)&ak[sr0][scol] = BUF0;                                          \
    *(float4*)&ak[sr1][scol] = BUF1;                                          \
    __syncthreads();                                                          \
    if ((CC) + 2 < 8) {                                                       \
      BUF0 = *(const float4*)(p0 + (size_t)((CC) + 2) * (64 * D));            \
      BUF1 = *(const float4*)(p1 + (size_t)((CC) + 2) * (64 * D));            \
    }                                                                         \
    __builtin_amdgcn_sched_barrier(0);                                        \
    float acc0 = 0.f, acc1 = 0.f;                                             \
    _Pragma("unroll")                                                         \
    for (int dc = 0; dc < D; dc += 8) {                                       \
      float4 x0 = *(const float4*)&ak[lane][dc];                              \
      float4 x1 = *(const float4*)&ak[lane][dc + 4];                          \
      float4 q0 = *(const float4*)(qh + dc);                                  \
      float4 q1 = *(const float4*)(qh + dc + 4);                              \
      acc0 = fmaf(q0.x, x0.x, fmaf(q0.y, x0.y,                                \
             fmaf(q0.z, x0.z, fmaf(q0.w, x0.w, acc0))));                      \
      acc1 = fmaf(q1.x, x1.x, fmaf(q1.y, x1.y,                                \
             fmaf(q1.z, x1.z, fmaf(q1.w, x1.w, acc1))));                      \
    }                                                                         \
    float s = s1v[CC] + (acc0 + acc1) * INV_TEMP;                             \
    sc[w][((CC) << 6) + lane] = (mv[CC] == 0) ? -10000.0f : s;                \
    __syncthreads();                                                          \
  }

__global__ __launch_bounds__(512, 4) void k2_fused(
    const float* __restrict__ q, const float* __restrict__ adj_k,
    const float* __restrict__ adj_v, const int* __restrict__ mask,
    const float* __restrict__ s1, float* __restrict__ out,
    float* __restrict__ attn) {
  const int b = blockIdx.x >> 9, i = blockIdx.x & (L - 1);
  const int t = threadIdx.x;
  const int lane = t & 63;
  const int w = __builtin_amdgcn_readfirstlane(t >> 6);   // wave id 0..7
  __shared__ float sc[NH][L];      // 16 KB: scores -> probs -> out-partials
  __shared__ float ak[64][68];     // 17 KB: adj_k chunk (stride 68)

  // ---------------- phase A: sc[h][j] = s1 + (q[h].adj_k[j])/8, masked -----
  {
    const float* akb = adj_k + ((size_t)b * L + i) * (size_t)(L * D);
    const float* qh  = q  + (((size_t)b * NH + w) * L + i) * D;  // uniform
    const float* s1r = s1 + (((size_t)b * NH + w) * L + i) * L;
    const int*   mr  = mask + b * L;
    const int sr0 = t >> 4, scol = (t & 15) << 2, sr1 = sr0 + 32;

    float s1v[8]; int mv[8];                   // all 8 chunks, one burst
#pragma unroll
    for (int m = 0; m < 8; ++m) {
      s1v[m] = s1r[(m << 6) + lane];
      mv[m]  = mr[(m << 6) + lane];
    }

    const float* p0 = akb + (size_t)sr0 * D + scol;
    const float* p1 = akb + (size_t)sr1 * D + scol;
    float4 bufA0 = *(const float4*)(p0);                 // chunk 0
    float4 bufA1 = *(const float4*)(p1);
    float4 bufB0 = *(const float4*)(p0 + 64 * D);        // chunk 1
    float4 bufB1 = *(const float4*)(p1 + 64 * D);

    K2_CHUNK(0, bufA0, bufA1)
    K2_CHUNK(1, bufB0, bufB1)
    K2_CHUNK(2, bufA0, bufA1)
    K2_CHUNK(3, bufB0, bufB1)
    K2_CHUNK(4, bufA0, bufA1)
    K2_CHUNK(5, bufB0, bufB1)
    K2_CHUNK(6, bufA0, bufA1)
    K2_CHUNK(7, bufB0, bufB1)
  }

  // ---------------- phase B: softmax, head w per wave ----------------------
  {
    float* arow = attn + (((size_t)b * NH + w) * L + i) * L;
    float vals[8];
    float mx = -3.4e38f;
#pragma unroll
    for (int m = 0; m < 8; ++m) {
      float s = sc[w][lane + (m << 6)];
      vals[m] = s;
      mx = fmaxf(mx, s);
    }
#pragma unroll
    for (int off = 32; off > 0; off >>= 1) mx = fmaxf(mx, __shfl_xor(mx, off, 64));
    float sum = 0.f;
#pragma unroll
    for (int m = 0; m < 8; ++m) { vals[m] = __expf(vals[m] - mx); sum += vals[m]; }
#pragma unroll
    for (int off = 32; off > 0; off >>= 1) sum += __shfl_xor(sum, off, 64);
    const float inv = 1.0f / sum;
#pragma unroll
    for (int m = 0; m < 8; ++m) {
      int jj = lane + (m << 6);
      float p = vals[m] * inv;
      arow[jj] = p;       // attn output (coalesced 256B stores)
      sc[w][jj] = p;      // reuse for phase C
    }
  }
  __syncthreads();

  // ---------------- phase C: out[h][d] = sum_j p[h][j]*adj_v[j][d] ---------
  {
    const int jb = w << 6;                     // wave's j-slice
    const int js = lane >> 4, dq = lane & 15;  // 4 j's per step, d = 4*dq
    const float* avb = adj_v + ((size_t)b * L + i) * (size_t)(L * D)
                             + (size_t)(jb + js) * D + 4 * dq;
    float4 av[16];                             // whole slice: 16-deep burst
#pragma unroll
    for (int u = 0; u < 16; ++u)
      av[u] = *(const float4*)(avb + (size_t)(u << 2) * D);
    __builtin_amdgcn_sched_barrier(0);         // pin: all 16 issued first
    float4 o[NH];
#pragma unroll
    for (int h = 0; h < NH; ++h) o[h] = make_float4(0.f, 0.f, 0.f, 0.f);
#pragma unroll
    for (int u = 0; u < 16; ++u) {
      const int j = jb + (u << 2) + js;
#pragma unroll
      for (int h = 0; h < NH; ++h) {
        float p = sc[h][j];                    // 4 addrs, 16-lane broadcast
        o[h].x = fmaf(p, av[u].x, o[h].x);
        o[h].y = fmaf(p, av[u].y, o[h].y);
        o[h].z = fmaf(p, av[u].z, o[h].z);
        o[h].w = fmaf(p, av[u].w, o[h].w);
      }
    }
#pragma unroll
    for (int h = 0; h < NH; ++h) {             // reduce over js (xor 16,32)
      o[h].x += __shfl_xor(o[h].x, 16, 64); o[h].x += __shfl_xor(o[h].x, 32, 64);
      o[h].y += __shfl_xor(o[h].y, 16, 64); o[h].y += __shfl_xor(o[h].y, 32, 64);
      o[h].z += __shfl_xor(o[h].z, 16, 64); o[h].z += __shfl_xor(o[h].z, 32, 64);
      o[h].w += __shfl_xor(o[h].w, 16, 64); o[h].w += __shfl_xor(o[h].w, 32, 64);
    }
    // ---- cross-wave combine ----
    __syncthreads();                           // all waves done reading probs
    float* opart = &sc[0][0];                  // [wave][head][64d] = 16 KB
    if (js == 0) {
#pragma unroll
      for (int h = 0; h < NH; ++h)
        *(float4*)(opart + (((w << 3) + h) << 6) + 4 * dq) = o[h];
    }
    __syncthreads();
    float r = 0.f;                             // wave w reduces head w, lane=d
#pragma unroll
    for (int wv = 0; wv < 8; ++wv) r += opart[(((wv << 3) + w) << 6) + lane];
    out[(((size_t)b * NH + w) * L + i) * D + lane] = r;
  }
}

// ---------------------------------------------------------------------------
// K3: out[b,h,i,d] += sum_j attn[b,h,i,j] * v[b,h,j,d]   (unchanged)
// ---------------------------------------------------------------------------
__global__ __launch_bounds__(256) void k3_av(const float* __restrict__ attn,
                                             const float* __restrict__ v,
                                             float* __restrict__ out) {
  const int bh = blockIdx.x, it = blockIdx.y;
  __shared__ float As[32][68];    // attn tile [i][j], b128-aligned reads
  __shared__ float Vt[64][65];    // v tile transposed [d][j], stride 65
  const int t = threadIdx.x;
  const float* ab = attn + ((size_t)bh * L + it * 32) * L;
  const float* vb = v + (size_t)bh * (size_t)(L * D);
  const int i0 = t >> 4, j0 = t & 15;         // i = i0+16m (m<2), d = j0+16n
  float acc[2][4] = {};
#pragma unroll 1
  for (int jc = 0; jc < L; jc += 64) {
    __syncthreads();
#pragma unroll
    for (int n0 = 0; n0 < 2; ++n0) {          // attn: 32x64 = 512 f4
      int n = t + (n0 << 8);
      int r = n >> 4, c = (n & 15) << 2;
      *(float4*)&As[r][c] = *(const float4*)(ab + (size_t)r * L + jc + c);
    }
#pragma unroll
    for (int n0 = 0; n0 < 4; ++n0) {          // v: 64x64 = 1024 f4, transpose
      int n = t + (n0 << 8);
      int r = n >> 4, c = (n & 15) << 2;
      float4 a = *(const float4*)(vb + (size_t)(jc + r) * D + c);
      Vt[c][r] = a.x; Vt[c + 1][r] = a.y; Vt[c + 2][r] = a.z; Vt[c + 3][r] = a.w;
    }
    __syncthreads();
#pragma unroll 1
    for (int kc = 0; kc < 64; kc += 4) {
      float4 a[2];
#pragma unroll
      for (int m = 0; m < 2; ++m) a[m] = *(const float4*)&As[i0 + 16 * m][kc];
      float bb[4][4];
#pragma unroll
      for (int n = 0; n < 4; ++n) {
        const float* vr = &Vt[j0 + 16 * n][kc];
        bb[n][0] = vr[0]; bb[n][1] = vr[1]; bb[n][2] = vr[2]; bb[n][3] = vr[3];
      }
#pragma unroll
      for (int m = 0; m < 2; ++m)
#pragma unroll
        for (int n = 0; n < 4; ++n)
          acc[m][n] = fmaf(a[m].x, bb[n][0],
                      fmaf(a[m].y, bb[n][1],
                      fmaf(a[m].z, bb[n][2],
                      fmaf(a[m].w, bb[n][3], acc[m][n]))));
    }
  }
  float* ob = out + ((size_t)bh * L + it * 32) * D;
#pragma unroll
  for (int m = 0; m < 2; ++m)
#pragma unroll
    for (int n = 0; n < 4; ++n) {
      float* p = ob + (size_t)(i0 + 16 * m) * D + j0 + 16 * n;
      *p += acc[m][n];                        // RMW; k2 ran first (same stream)
    }
}

// ---------------------------------------------------------------------------
extern "C" void kernel_launch(void* const* d_in, const int* in_sizes, int n_in,
                              void* d_out, int out_size, void* d_ws, size_t ws_size,
                              hipStream_t stream) {
  const float* q     = (const float*)d_in[0];
  const float* k     = (const float*)d_in[1];
  const float* v     = (const float*)d_in[2];
  const float* adj_k = (const float*)d_in[3];
  const float* adj_v = (const float*)d_in[4];
  const int*   mask  = (const int*)d_in[5];
  float* out  = (float*)d_out;
  float* attn = out + (size_t)B * NH * L * D;   // second output region
  float* s1   = (float*)d_ws;                   // B*NH*L*L fp32 = 16.8 MB

  dim3 g1(B * NH, L / 64, L / 64);
  k1_qk<<<g1, 256, 0, stream>>>(q, k, s1);
  k2_fused<<<B * L, 512, 0, stream>>>(q, adj_k, adj_v, mask, s1, out, attn);
  dim3 g3(B * NH, L / 32);
  k3_av<<<g3, 256, 0, stream>>>(attn, v, out);
}